// Round 1
// 758.912 us; speedup vs baseline: 1.4837x; 1.4837x over previous
//
#include <hip/hip_runtime.h>

#define NN 10000
#define NE 160000

typedef unsigned short u16;
typedef __bf16 bf16x8 __attribute__((ext_vector_type(8)));
typedef float f32x4 __attribute__((ext_vector_type(4)));

#define INV_SQRT3 0.57735026918962576451f
#define INV_SQRT2 0.70710678118654752440f
#define LIN_SCALE 0.08838834764831845f

// ws layout (agg lives in d_out to stay well under any ws_size limit)
#define H3_OFF    0                  // E*64 bf16 = 20,480,000 B
#define WM4_OFF   20480000           // 40960 u16 = 81,920 B
#define WSW_OFF   20561920           // 4 * 16384 u16 = 131,072 B

__device__ __forceinline__ u16 f2bf(float f){
  union { float f; unsigned u; } v; v.f = f;
  unsigned r = v.u + 0x7fffu + ((v.u >> 16) & 1u);
  return (u16)(r >> 16);
}
__device__ __forceinline__ float silu_f(float x){
  return x / (1.f + __expf(-x));
}

union Frag { uint4 u4; bf16x8 bf; };

// ---------------------------------------------------------------- P0: weight swizzle (fp32 -> bf16 B-fragments)
__global__ __launch_bounds__(256) void prep_weights(
    const float* __restrict__ Wm4, const float* __restrict__ rW0, const float* __restrict__ rW1,
    const float* __restrict__ sW0, const float* __restrict__ sW1,
    u16* __restrict__ wm4s, u16* __restrict__ wsw){
  int t  = blockIdx.x * blockDim.x + threadIdx.x;
  int nt = gridDim.x * blockDim.x;
  for (int idx = t; idx < 40960; idx += nt){           // Wm4: (64,640), 40 ct x 2 ks
    int jj = idx & 7; int lane = (idx >> 3) & 63; int blk = idx >> 9;
    int ks = blk & 1; int ct = blk >> 1;
    int k = ks*32 + ((lane >> 4) << 3) + jj;
    int col = ct*16 + (lane & 15);
    wm4s[idx] = f2bf(Wm4[k*640 + col]);
  }
  const float* Ws[4] = { rW0, rW1, sW0, sW1 };
  for (int m = 0; m < 4; ++m){
    const float* src = Ws[m];
    u16* dst = wsw + m*16384;
    for (int idx = t; idx < 16384; idx += nt){         // (128,128), 8 ct x 4 ks
      int jj = idx & 7; int lane = (idx >> 3) & 63; int blk = idx >> 9;
      int ks = blk & 3; int ct = blk >> 2;
      int k = ks*32 + ((lane >> 4) << 3) + jj;
      int col = ct*16 + (lane & 15);
      dst[idx] = f2bf(src[k*128 + col]);
    }
  }
}

// ---------------------------------------------------------------- K0: zero agg (= d_out)
__global__ __launch_bounds__(256) void zero_agg(float* __restrict__ agg){
  int t = blockIdx.x * blockDim.x + threadIdx.x;
  f32x4* p = (f32x4*)agg;
  const int n4 = NN*512/4;
  for (int i = t; i < n4; i += gridDim.x * blockDim.x){
    f32x4 z = {0.f,0.f,0.f,0.f}; p[i] = z;
  }
}

// ---------------------------------------------------------------- K1: h3 = silu(silu(silu(e@Wm1)@Wm2)@Wm3), bf16 out
__global__ __launch_bounds__(256) void radial_h3_kernel(
    const float* __restrict__ emb, const float* __restrict__ Wm1,
    const float* __restrict__ Wm2, const float* __restrict__ Wm3,
    u16* __restrict__ h3){
  __shared__ float s_emb[64*12];
  __shared__ float s_w1[8*64];
  __shared__ float s_w2[64*68];
  __shared__ float s_w3[64*68];
  __shared__ float s_ha[64*65];
  __shared__ float s_hb[64*65];
  int t = threadIdx.x;
  int e0 = blockIdx.x * 64;
  if (t < 64){
    const float4* src = (const float4*)(emb + (size_t)(e0 + t)*8);
    float4 v0 = src[0], v1 = src[1];
    float* r = s_emb + t*12;
    r[0]=v0.x; r[1]=v0.y; r[2]=v0.z; r[3]=v0.w;
    r[4]=v1.x; r[5]=v1.y; r[6]=v1.z; r[7]=v1.w;
  }
  for (int idx = t; idx < 512; idx += 256) s_w1[idx] = Wm1[idx];
  for (int idx = t; idx < 4096; idx += 256){
    int k = idx >> 6, d = idx & 63;
    s_w2[k*68 + d] = Wm2[idx];
    s_w3[k*68 + d] = Wm3[idx];
  }
  __syncthreads();
  int p  = t >> 3;       // 0..31 -> edges 2p, 2p+1
  int dg = t & 7;        // outputs dg*8 .. dg*8+7
  int ea = 2*p, eb = 2*p + 1;
  float acc0[8], acc1[8];
  // layer 1 (K=8)
  #pragma unroll
  for (int j = 0; j < 8; ++j){ acc0[j]=0.f; acc1[j]=0.f; }
  #pragma unroll
  for (int k = 0; k < 8; ++k){
    float h0 = s_emb[ea*12 + k], h1 = s_emb[eb*12 + k];
    #pragma unroll
    for (int j = 0; j < 8; ++j){
      float wv = s_w1[k*64 + dg*8 + j];
      acc0[j] = fmaf(h0, wv, acc0[j]); acc1[j] = fmaf(h1, wv, acc1[j]);
    }
  }
  #pragma unroll
  for (int j = 0; j < 8; ++j){
    s_ha[ea*65 + dg*8 + j] = silu_f(acc0[j]);
    s_ha[eb*65 + dg*8 + j] = silu_f(acc1[j]);
  }
  __syncthreads();
  // layer 2 (K=64)
  #pragma unroll
  for (int j = 0; j < 8; ++j){ acc0[j]=0.f; acc1[j]=0.f; }
  #pragma unroll 4
  for (int k = 0; k < 64; ++k){
    float h0 = s_ha[ea*65 + k], h1 = s_ha[eb*65 + k];
    float wv[8];
    *(f32x4*)&wv[0] = *(const f32x4*)&s_w2[k*68 + dg*8];
    *(f32x4*)&wv[4] = *(const f32x4*)&s_w2[k*68 + dg*8 + 4];
    #pragma unroll
    for (int j = 0; j < 8; ++j){
      acc0[j] = fmaf(h0, wv[j], acc0[j]); acc1[j] = fmaf(h1, wv[j], acc1[j]);
    }
  }
  #pragma unroll
  for (int j = 0; j < 8; ++j){
    s_hb[ea*65 + dg*8 + j] = silu_f(acc0[j]);
    s_hb[eb*65 + dg*8 + j] = silu_f(acc1[j]);
  }
  __syncthreads();
  // layer 3 (K=64) -> global bf16
  #pragma unroll
  for (int j = 0; j < 8; ++j){ acc0[j]=0.f; acc1[j]=0.f; }
  #pragma unroll 4
  for (int k = 0; k < 64; ++k){
    float h0 = s_hb[ea*65 + k], h1 = s_hb[eb*65 + k];
    float wv[8];
    *(f32x4*)&wv[0] = *(const f32x4*)&s_w3[k*68 + dg*8];
    *(f32x4*)&wv[4] = *(const f32x4*)&s_w3[k*68 + dg*8 + 4];
    #pragma unroll
    for (int j = 0; j < 8; ++j){
      acc0[j] = fmaf(h0, wv[j], acc0[j]); acc1[j] = fmaf(h1, wv[j], acc1[j]);
    }
  }
  union { u16 s[8]; uint4 v; } o0, o1;
  #pragma unroll
  for (int j = 0; j < 8; ++j){
    o0.s[j] = f2bf(silu_f(acc0[j]));
    o1.s[j] = f2bf(silu_f(acc1[j]));
  }
  *(uint4*)(h3 + (size_t)(e0 + ea)*64 + dg*8) = o0.v;
  *(uint4*)(h3 + (size_t)(e0 + eb)*64 + dg*8) = o1.v;
}

// ---------------------------------------------------------------- K2: fused w-GEMM + message + atomic scatter
// one block = 16 edges; w = h3 @ Wm4 via MFMA into LDS; comb loaded direct from global
// Atomic repack: every atomic instruction's 16 lanes cover ONE contiguous 64-B line.
// m1 values are redistributed across the 16-lane edge group via __shfl so that
// lane l adds flat vector element 48j+16i+l (i=0..2). 80 -> 32 line-RMWs per edge.
__global__ __launch_bounds__(256) void edge_msg_kernel(
    const float* __restrict__ nf, const float* __restrict__ ef, const float* __restrict__ attrs,
    const int* __restrict__ snd, const int* __restrict__ rcv,
    const u16* __restrict__ h3, const u16* __restrict__ wm4s, float* __restrict__ agg){
  __shared__ float s_w[16*650];     // w (16 edges x 640), stride 650 to spread banks
  int t = threadIdx.x;
  int lane = t & 63, wave = t >> 6;
  int e0 = blockIdx.x << 4;
  // MFMA: w[16][640] = h3_tile[16][64] @ Wm4[64][640]; each wave: 10 col-tiles
  Frag a0f, a1f;
  const u16* h3r = h3 + (size_t)(e0 + (lane & 15))*64 + ((lane >> 4) << 3);
  a0f.u4 = *(const uint4*)(h3r);
  a1f.u4 = *(const uint4*)(h3r + 32);
  int colb = lane & 15;
  int rowb = (lane >> 4) << 2;
  #pragma unroll
  for (int i = 0; i < 10; ++i){
    int ct = wave*10 + i;
    const u16* bp = wm4s + ((size_t)ct*128 + lane)*8;
    Frag b0f, b1f;
    b0f.u4 = *(const uint4*)(bp);
    b1f.u4 = *(const uint4*)(bp + 512);
    f32x4 acc = {0.f,0.f,0.f,0.f};
    acc = __builtin_amdgcn_mfma_f32_16x16x32_bf16(a0f.bf, b0f.bf, acc, 0, 0, 0);
    acc = __builtin_amdgcn_mfma_f32_16x16x32_bf16(a1f.bf, b1f.bf, acc, 0, 0, 0);
    int cb = ct*16 + colb;
    #pragma unroll
    for (int r = 0; r < 4; ++r) s_w[(rowb + r)*650 + cb] = acc[r];
  }
  __syncthreads();
  // messages + scatter: 16 threads per edge
  int er = t >> 4, l16 = t & 15;
  int eg = e0 + er;
  int si = snd[eg], ri = rcv[eg];
  float4 at = *(const float4*)(attrs + (size_t)eg*4);
  float sh0 = at.x, s1x = at.y, s1y = at.z, s1z = at.w;
  const float* ps = nf + (size_t)si*512;
  const float* pr = nf + (size_t)ri*512;
  const float* pe = ef + (size_t)eg*512;
  float* ar = agg + (size_t)ri*512;
  const float* wr = s_w + er*650;
  // lane-permutation constants for contiguous m1 atomics:
  // target flat g_i = 16*i + l16 -> source lane s_i = g_i/3, component c_i = g_i%3
  const int lb = t & 48;                 // 16-lane group base within the wave
  const int g0i = l16, g1i = 16 + l16, g2i = 32 + l16;
  const int sl0 = g0i/3, sl1 = g1i/3, sl2 = g2i/3;
  const int cp0 = g0i - 3*sl0, cp1 = g1i - 3*sl1, cp2 = g2i - 3*sl2;
  #pragma unroll
  for (int j = 0; j < 8; ++j){
    int c = j*16 + l16;
    float x0 = ps[c] + pr[c] + pe[c];
    int vb = 128 + 3*c;
    float xa = ps[vb]   + pr[vb]   + pe[vb];
    float xv = ps[vb+1] + pr[vb+1] + pe[vb+1];
    float xc = ps[vb+2] + pr[vb+2] + pe[vb+2];
    float w0 = wr[c], w1 = wr[128 + c], w2 = wr[256 + c], w3 = wr[384 + c], w4 = wr[512 + c];
    float dot = xa*s1x + xv*s1y + xc*s1z;
    float m0 = w0*x0*sh0 + w1*dot*INV_SQRT3;
    float cr0 = xv*s1z - xc*s1y;
    float cr1 = xc*s1x - xa*s1z;
    float cr2 = xa*s1y - xv*s1x;
    float m1x = w2*xa*sh0 + w3*x0*s1x + w4*cr0*INV_SQRT2;
    float m1y = w2*xv*sh0 + w3*x0*s1y + w4*cr1*INV_SQRT2;
    float m1z = w2*xc*sh0 + w3*x0*s1z + w4*cr2*INV_SQRT2;
    // m0: 16 lanes x 4B contiguous (64-B line) — unchanged
    unsafeAtomicAdd(ar + c, m0);
    // m1: redistribute so each of the 3 atomic instrs covers one 64-B line
    float t0x = __shfl(m1x, lb + sl0); float t0y = __shfl(m1y, lb + sl0); float t0z = __shfl(m1z, lb + sl0);
    float t1x = __shfl(m1x, lb + sl1); float t1y = __shfl(m1y, lb + sl1); float t1z = __shfl(m1z, lb + sl1);
    float t2x = __shfl(m1x, lb + sl2); float t2y = __shfl(m1y, lb + sl2); float t2z = __shfl(m1z, lb + sl2);
    float v0 = (cp0 == 0) ? t0x : ((cp0 == 1) ? t0y : t0z);
    float v1 = (cp1 == 0) ? t1x : ((cp1 == 1) ? t1y : t1z);
    float v2 = (cp2 == 0) ? t2x : ((cp2 == 1) ? t2y : t2z);
    float* vbase = ar + 128 + 48*j;
    unsafeAtomicAdd(vbase + l16,      v0);
    unsafeAtomicAdd(vbase + 16 + l16, v1);
    unsafeAtomicAdd(vbase + 32 + l16, v2);
  }
}

// ---------------------------------------------------------------- K3: out = agg + EL(agg,res) + EL(nf,skip); agg IS out (in-place)
__global__ __launch_bounds__(256) void out_kernel(
    const float* __restrict__ nf, const u16* __restrict__ wsw, float* __restrict__ out){
  __shared__ u16 s_a0[16*136];
  __shared__ u16 s_a1[3][16*136];
  __shared__ u16 s_n0[16*136];
  __shared__ u16 s_n1[3][16*136];
  int t = threadIdx.x;
  int lane = t & 63, wave = t >> 6;
  int n0b = blockIdx.x << 4;
  int nr = t >> 4, l16 = t & 15;
  int node = n0b + nr;
  const float* arow = out + (size_t)node*512;
  const float* nrow = nf  + (size_t)node*512;
  #pragma unroll
  for (int jj = 0; jj < 8; ++jj){
    int c = l16 + jj*16;
    s_a0[nr*136 + c] = f2bf(arow[c]);
    s_n0[nr*136 + c] = f2bf(nrow[c]);
    #pragma unroll
    for (int i = 0; i < 3; ++i){
      s_a1[i][nr*136 + c] = f2bf(arow[128 + 3*c + i]);
      s_n1[i][nr*136 + c] = f2bf(nrow[128 + 3*c + i]);
    }
  }
  __syncthreads();
  int m15 = lane & 15, quad = lane >> 4;
  int aoff = m15*136 + (quad << 3);
  #pragma unroll
  for (int i8 = 0; i8 < 8; ++i8){
    int tt = wave*8 + i8;
    const u16 *Ag, *An, *Bg, *Bn;
    int dt, vi = 0;
    bool scalar = (tt < 8);
    if (scalar){ dt = tt; Ag = s_a0; An = s_n0; Bg = wsw; Bn = wsw + 2*16384; }
    else { vi = (tt - 8) >> 3; dt = (tt - 8) & 7; Ag = s_a1[vi]; An = s_n1[vi]; Bg = wsw + 16384; Bn = wsw + 3*16384; }
    f32x4 acc = {0.f,0.f,0.f,0.f};
    #pragma unroll
    for (int ks = 0; ks < 4; ++ks){
      Frag a, b;
      a.u4 = *(const uint4*)(Ag + aoff + ks*32);
      b.u4 = *(const uint4*)(Bg + ((size_t)(dt*4 + ks)*64 + lane)*8);
      acc = __builtin_amdgcn_mfma_f32_16x16x32_bf16(a.bf, b.bf, acc, 0, 0, 0);
    }
    #pragma unroll
    for (int ks = 0; ks < 4; ++ks){
      Frag a, b;
      a.u4 = *(const uint4*)(An + aoff + ks*32);
      b.u4 = *(const uint4*)(Bn + ((size_t)(dt*4 + ks)*64 + lane)*8);
      acc = __builtin_amdgcn_mfma_f32_16x16x32_bf16(a.bf, b.bf, acc, 0, 0, 0);
    }
    int d = dt*16 + m15;
    int idx = scalar ? d : (128 + 3*d + vi);
    #pragma unroll
    for (int r = 0; r < 4; ++r){
      int nd = n0b + quad*4 + r;
      float val = acc[r]*LIN_SCALE + out[(size_t)nd*512 + idx];
      out[(size_t)nd*512 + idx] = val;
    }
  }
}

extern "C" void kernel_launch(void* const* d_in, const int* in_sizes, int n_in,
                              void* d_out, int out_size, void* d_ws, size_t ws_size,
                              hipStream_t stream){
  (void)in_sizes; (void)n_in; (void)out_size; (void)ws_size;
  const float* nf    = (const float*)d_in[0];
  const float* ef    = (const float*)d_in[1];
  const float* attrs = (const float*)d_in[2];
  const float* emb   = (const float*)d_in[3];
  const int* snd     = (const int*)d_in[4];
  const int* rcv     = (const int*)d_in[5];
  const float* Wm1   = (const float*)d_in[6];
  const float* Wm2   = (const float*)d_in[7];
  const float* Wm3   = (const float*)d_in[8];
  const float* Wm4   = (const float*)d_in[9];
  const float* rW0   = (const float*)d_in[10];
  const float* rW1   = (const float*)d_in[11];
  const float* sW0   = (const float*)d_in[12];
  const float* sW1   = (const float*)d_in[13];
  char* ws  = (char*)d_ws;
  u16* h3   = (u16*)(ws + H3_OFF);
  u16* wm4s = (u16*)(ws + WM4_OFF);
  u16* wsw  = (u16*)(ws + WSW_OFF);
  float* out = (float*)d_out;

  prep_weights<<<dim3(80), dim3(256), 0, stream>>>(Wm4, rW0, rW1, sW0, sW1, wm4s, wsw);
  zero_agg<<<dim3(1280), dim3(256), 0, stream>>>(out);
  radial_h3_kernel<<<dim3(NE/64), dim3(256), 0, stream>>>(emb, Wm1, Wm2, Wm3, h3);
  edge_msg_kernel<<<dim3(NE/16), dim3(256), 0, stream>>>(nf, ef, attrs, snd, rcv, h3, wm4s, out);
  out_kernel<<<dim3(NN/16), dim3(256), 0, stream>>>(nf, wsw, out);
}